// Round 1
// baseline (586.304 us; speedup 1.0000x reference)
//
#include <hip/hip_runtime.h>

#define NTOK 4096
#define DIMC 1024
#define HEADS 12
#define DH 8
#define QSCALE 0.35355339059327373f   /* 8^-0.5 */
#define LOG2E  1.4426950408889634f
#define LN2    0.6931471805599453f

// ---------------- Kernel 1: proj = x @ W^T, write q*SCALE and k into ws ----
// ws layout: qk[qkflag][h][n][d]  (qkflag 0=q scaled, 1=k), 2*12*4096*8 floats = 3 MB
// grid 256 blocks (16 rows each) x 256 threads
__global__ __launch_bounds__(256) void k1_proj(const float* __restrict__ x,
                                               const float* __restrict__ W,
                                               float* __restrict__ qk) {
    __shared__ float xs[16 * 1028];        // pad 1024->1028 to break bank aliasing
    const int t = threadIdx.x;
    const int row0 = blockIdx.x * 16;

    // cooperative coalesced load of the 16x1024 x tile (4096 float4)
    const float4* x4 = (const float4*)(x + (size_t)row0 * DIMC);
    #pragma unroll
    for (int i = 0; i < 16; ++i) {
        int f = t + i * 256;               // float4 index within tile
        int r = f >> 8;                    // 256 float4 per row
        int c4 = f & 255;
        float4 v = x4[f];
        *(float4*)(&xs[r * 1028 + c4 * 4]) = v;
    }
    __syncthreads();

    const int g  = t >> 2;                 // 0..63 -> owns o = 3g..3g+2 (quad-broadcast W)
    const int rg = t & 3;                  // owns rows rg*4 .. rg*4+3

    float acc[4][3];
    #pragma unroll
    for (int a = 0; a < 4; ++a)
        #pragma unroll
        for (int m = 0; m < 3; ++m) acc[a][m] = 0.f;

    const float* w0 = W + (size_t)(3 * g) * DIMC;
    for (int c = 0; c < DIMC; c += 4) {
        float4 w[3];
        #pragma unroll
        for (int m = 0; m < 3; ++m)
            w[m] = *(const float4*)(w0 + (size_t)m * DIMC + c);
        #pragma unroll
        for (int a = 0; a < 4; ++a) {
            float4 xv = *(const float4*)(&xs[(rg * 4 + a) * 1028 + c]);
            #pragma unroll
            for (int m = 0; m < 3; ++m) {
                acc[a][m] = fmaf(xv.x, w[m].x,
                            fmaf(xv.y, w[m].y,
                            fmaf(xv.z, w[m].z,
                            fmaf(xv.w, w[m].w, acc[a][m]))));
            }
        }
    }

    #pragma unroll
    for (int m = 0; m < 3; ++m) {
        int o   = 3 * g + m;
        int qkf = (o >= 96) ? 1 : 0;
        int oo  = o - 96 * qkf;
        int h   = oo >> 3;
        int d   = oo & 7;
        #pragma unroll
        for (int a = 0; a < 4; ++a) {
            int n = row0 + rg * 4 + a;
            float v = acc[a][m];
            if (!qkf) v *= QSCALE;
            qk[((size_t)qkf * HEADS + h) * ((size_t)NTOK * DH) + (size_t)n * DH + d] = v;
        }
    }
}

// ---------------- Kernel 2: gates row: logsigmoid(q_i . k_j) masked j<i,
//                  reverse cumsum over j, one block per (h,i) ----------------
__device__ __forceinline__ float log_sigmoid(float s) {
    float mn = fminf(s, 0.f);
    float z  = __builtin_amdgcn_exp2f(fabsf(s) * -LOG2E);   // = exp(-|s|)
    return mn - LN2 * __builtin_amdgcn_logf(1.f + z);       // log2 -> *ln2
}

__global__ __launch_bounds__(256) void k2_gates(const float* __restrict__ qk,
                                                float* __restrict__ out) {
    const int bid  = blockIdx.x;
    const int i    = bid & (NTOK - 1);
    const int h    = bid >> 12;
    const int t    = threadIdx.x;
    const int lane = t & 63;
    const int wid  = t >> 6;

    const float* qrow  = qk + ((size_t)h * NTOK + i) * DH;          // pre-scaled q
    const float* kbase = qk + ((size_t)(HEADS + h) * NTOK) * DH;

    const float4 q0 = *(const float4*)(qrow);
    const float4 q1 = *(const float4*)(qrow + 4);

    const int j0 = t * 16;
    float g[16];
    #pragma unroll
    for (int e = 0; e < 16; ++e) g[e] = 0.f;

    int jmax = i - j0;                      // strict: j < i
    if (jmax > 16) jmax = 16;

    if (jmax >= 16) {
        #pragma unroll
        for (int e = 0; e < 16; ++e) {
            const float* kp = kbase + (size_t)(j0 + e) * DH;
            float4 k0 = *(const float4*)(kp);
            float4 k1 = *(const float4*)(kp + 4);
            float s = fmaf(q0.x, k0.x, fmaf(q0.y, k0.y, fmaf(q0.z, k0.z,
                      fmaf(q0.w, k0.w, fmaf(q1.x, k1.x, fmaf(q1.y, k1.y,
                      fmaf(q1.z, k1.z, q1.w * k1.w)))))));
            g[e] = log_sigmoid(s);
        }
    } else if (jmax > 0) {
        for (int e = 0; e < jmax; ++e) {
            const float* kp = kbase + (size_t)(j0 + e) * DH;
            float4 k0 = *(const float4*)(kp);
            float4 k1 = *(const float4*)(kp + 4);
            float s = fmaf(q0.x, k0.x, fmaf(q0.y, k0.y, fmaf(q0.z, k0.z,
                      fmaf(q0.w, k0.w, fmaf(q1.x, k1.x, fmaf(q1.y, k1.y,
                      fmaf(q1.z, k1.z, q1.w * k1.w)))))));
            g[e] = log_sigmoid(s);
        }
    }

    // local reverse inclusive suffix within the 16-element chunk
    float run = 0.f;
    #pragma unroll
    for (int e = 15; e >= 0; --e) { run += g[e]; g[e] = run; }

    // intra-wave inclusive suffix scan of per-thread totals
    float s = run;
    #pragma unroll
    for (int off = 1; off < 64; off <<= 1) {
        float v = __shfl_down(s, off, 64);
        if (lane + off < 64) s += v;
    }
    const float exclw = s - run;            // lanes strictly after me, same wave

    __shared__ float wt[4];
    if (lane == 0) wt[wid] = s;             // wave total (lane 0 inclusive suffix)
    __syncthreads();
    float exclc = 0.f;
    #pragma unroll
    for (int w = 0; w < 4; ++w)
        if (w > wid) exclc += wt[w];
    const float base = exclw + exclc;

    float* orow = out + ((size_t)h * NTOK + i) * NTOK + j0;
    #pragma unroll
    for (int e4 = 0; e4 < 4; ++e4) {
        float4 v;
        v.x = g[e4 * 4 + 0] + base;
        v.y = g[e4 * 4 + 1] + base;
        v.z = g[e4 * 4 + 2] + base;
        v.w = g[e4 * 4 + 3] + base;
        *(float4*)(orow + e4 * 4) = v;
    }
}

extern "C" void kernel_launch(void* const* d_in, const int* in_sizes, int n_in,
                              void* d_out, int out_size, void* d_ws, size_t ws_size,
                              hipStream_t stream) {
    const float* x = (const float*)d_in[0];
    const float* W = (const float*)d_in[1];
    float* out = (float*)d_out;
    float* qk  = (float*)d_ws;               // 3 MB scratch: [2][12][4096][8] f32

    hipLaunchKernelGGL(k1_proj, dim3(NTOK / 16), dim3(256), 0, stream, x, W, qk);
    hipLaunchKernelGGL(k2_gates, dim3(HEADS * NTOK), dim3(256), 0, stream, qk, out);
}

// Round 2
// 360.294 us; speedup vs baseline: 1.6273x; 1.6273x over previous
//
#include <hip/hip_runtime.h>

#define NTOK 4096
#define DIMC 1024
#define HEADS 12
#define DH 8
#define QSCALE 0.35355339059327373f   /* 8^-0.5 */
#define LOG2E  1.4426950408889634f
#define LN2    0.6931471805599453f

// ws layout (floats):
//   Q:  [h][n][8]   (pre-scaled by QSCALE), offset 0,      12*4096*8 = 393216
//   K:  [h][d][n]   SoA,                    offset KOFF,   12*8*4096 = 393216
#define KOFF (HEADS * NTOK * DH)

// ---------------- Kernel 1: proj = x @ W^T -> q (AoS, scaled), k (SoA) -----
__global__ __launch_bounds__(256) void k1_proj(const float* __restrict__ x,
                                               const float* __restrict__ W,
                                               float* __restrict__ qk) {
    __shared__ float xs[16 * 1028];        // pad 1024->1028 to break bank aliasing
    const int t = threadIdx.x;
    const int row0 = blockIdx.x * 16;

    const float4* x4 = (const float4*)(x + (size_t)row0 * DIMC);
    #pragma unroll
    for (int i = 0; i < 16; ++i) {
        int f = t + i * 256;
        int r = f >> 8;
        int c4 = f & 255;
        float4 v = x4[f];
        *(float4*)(&xs[r * 1028 + c4 * 4]) = v;
    }
    __syncthreads();

    const int g  = t >> 2;                 // 0..63 -> owns o = 3g..3g+2
    const int rg = t & 3;                  // owns rows rg*4 .. rg*4+3

    float acc[4][3];
    #pragma unroll
    for (int a = 0; a < 4; ++a)
        #pragma unroll
        for (int m = 0; m < 3; ++m) acc[a][m] = 0.f;

    const float* w0 = W + (size_t)(3 * g) * DIMC;
    for (int c = 0; c < DIMC; c += 4) {
        float4 w[3];
        #pragma unroll
        for (int m = 0; m < 3; ++m)
            w[m] = *(const float4*)(w0 + (size_t)m * DIMC + c);
        #pragma unroll
        for (int a = 0; a < 4; ++a) {
            float4 xv = *(const float4*)(&xs[(rg * 4 + a) * 1028 + c]);
            #pragma unroll
            for (int m = 0; m < 3; ++m) {
                acc[a][m] = fmaf(xv.x, w[m].x,
                            fmaf(xv.y, w[m].y,
                            fmaf(xv.z, w[m].z,
                            fmaf(xv.w, w[m].w, acc[a][m]))));
            }
        }
    }

    #pragma unroll
    for (int m = 0; m < 3; ++m) {
        int o   = 3 * g + m;
        int qkf = (o >= 96) ? 1 : 0;
        int oo  = o - 96 * qkf;
        int h   = oo >> 3;
        int d   = oo & 7;
        #pragma unroll
        for (int a = 0; a < 4; ++a) {
            int n = row0 + rg * 4 + a;
            float v = acc[a][m];
            if (!qkf) {
                // Q: AoS [h][n][8], pre-scaled
                qk[((size_t)h * NTOK + n) * DH + d] = v * QSCALE;
            } else {
                // K: SoA [h][d][n]
                qk[KOFF + ((size_t)h * DH + d) * NTOK + n] = v;
            }
        }
    }
}

// ---------------- Kernel 2: gates row, one block per (h,i) -----------------
__device__ __forceinline__ float log_sigmoid(float s) {
    float mn = fminf(s, 0.f);
    float z  = __builtin_amdgcn_exp2f(fabsf(s) * -LOG2E);   // = exp(-|s|)
    return mn - LN2 * __builtin_amdgcn_logf(1.f + z);       // log2 -> *ln2
}

__global__ __launch_bounds__(256) void k2_gates(const float* __restrict__ qk,
                                                float* __restrict__ out) {
    const int bid  = blockIdx.x;
    const int i    = bid & (NTOK - 1);
    const int h    = bid >> 12;
    const int t    = threadIdx.x;
    const int lane = t & 63;
    const int wid  = t >> 6;

    // q row (uniform address -> scalar loads)
    const float* qrow = qk + ((size_t)h * NTOK + i) * DH;
    float q0 = qrow[0], q1 = qrow[1], q2 = qrow[2], q3 = qrow[3];
    float q4 = qrow[4], q5 = qrow[5], q6 = qrow[6], q7 = qrow[7];

    const float* ks = qk + KOFF + (size_t)h * DH * NTOK;

    float g[4][4];
    float tot[4], suf[4];

    #pragma unroll
    for (int c = 0; c < 4; ++c) {
        const int jb = c * 1024 + 4 * t;            // first j this thread owns in chunk c
        #pragma unroll
        for (int e = 0; e < 4; ++e) g[c][e] = 0.f;

        // wave-uniform skip: this wave's chunk covers j in [c*1024+256*wid, +256)
        if (c * 1024 + 256 * wid < i) {
            float s0 = 0.f, s1 = 0.f, s2 = 0.f, s3 = 0.f;
            #pragma unroll
            for (int d = 0; d < 8; ++d) {
                float4 kv = *(const float4*)(ks + (size_t)d * NTOK + jb); // coalesced
                float qd = (d == 0) ? q0 : (d == 1) ? q1 : (d == 2) ? q2 : (d == 3) ? q3
                         : (d == 4) ? q4 : (d == 5) ? q5 : (d == 6) ? q6 : q7;
                s0 = fmaf(qd, kv.x, s0);
                s1 = fmaf(qd, kv.y, s1);
                s2 = fmaf(qd, kv.z, s2);
                s3 = fmaf(qd, kv.w, s3);
            }
            if (jb + 0 < i) g[c][0] = log_sigmoid(s0);
            if (jb + 1 < i) g[c][1] = log_sigmoid(s1);
            if (jb + 2 < i) g[c][2] = log_sigmoid(s2);
            if (jb + 3 < i) g[c][3] = log_sigmoid(s3);
        }
    }

    // local reverse-inclusive suffix within each 4-elem group
    #pragma unroll
    for (int c = 0; c < 4; ++c) {
        g[c][2] += g[c][3];
        g[c][1] += g[c][2];
        g[c][0] += g[c][1];
        tot[c] = g[c][0];
    }

    // per-chunk wave-wide inclusive suffix scan of per-thread totals
    #pragma unroll
    for (int c = 0; c < 4; ++c) {
        float s = tot[c];
        #pragma unroll
        for (int off = 1; off < 64; off <<= 1) {
            float v = __shfl_down(s, off, 64);
            if (lane + off < 64) s += v;
        }
        suf[c] = s;                       // inclusive suffix within wave (this chunk)
    }

    // cross-(chunk,wave) suffix over 16 ordered entries (c major, wid minor)
    __shared__ float wt[16];
    if (lane == 0) {
        #pragma unroll
        for (int c = 0; c < 4; ++c) wt[c * 4 + wid] = suf[c];
    }
    __syncthreads();
    if (t < 16) {
        float v = wt[t];
        #pragma unroll
        for (int off = 1; off < 16; off <<= 1) {
            float u = __shfl_down(v, off, 64);
            if (t + off < 16) v += u;
        }
        wt[t] = v;                        // inclusive suffix over the 16 entries
    }
    __syncthreads();

    float* orow = out + ((size_t)h * NTOK + i) * NTOK;
    #pragma unroll
    for (int c = 0; c < 4; ++c) {
        int idx = c * 4 + wid + 1;
        float base  = (idx < 16) ? wt[idx] : 0.f;    // entries strictly after (c,wid)
        float add   = (suf[c] - tot[c]) + base;      // later lanes in wave + later entries
        float4 v;
        v.x = g[c][0] + add;
        v.y = g[c][1] + add;
        v.z = g[c][2] + add;
        v.w = g[c][3] + add;
        *(float4*)(orow + c * 1024 + 4 * t) = v;     // coalesced: wave covers 1024B
    }
}

extern "C" void kernel_launch(void* const* d_in, const int* in_sizes, int n_in,
                              void* d_out, int out_size, void* d_ws, size_t ws_size,
                              hipStream_t stream) {
    const float* x = (const float*)d_in[0];
    const float* W = (const float*)d_in[1];
    float* out = (float*)d_out;
    float* qk  = (float*)d_ws;               // 3 MB scratch

    hipLaunchKernelGGL(k1_proj, dim3(NTOK / 16), dim3(256), 0, stream, x, W, qk);
    hipLaunchKernelGGL(k2_gates, dim3(HEADS * NTOK), dim3(256), 0, stream, qk, out);
}

// Round 3
// 216.555 us; speedup vs baseline: 2.7074x; 1.6638x over previous
//
#include <hip/hip_runtime.h>

#define NTOK 4096
#define DIMC 1024
#define HEADS 12
#define DH 8
#define QSCALE 0.35355339059327373f   /* 8^-0.5 */
#define LOG2E  1.4426950408889634f
#define LN2    0.6931471805599453f

// ws layout (floats):
//   Q:  [h][n][8]   (pre-scaled by QSCALE), offset 0,      12*4096*8
//   K:  [h][d][n]   SoA,                    offset KOFF,   12*8*4096
#define KOFF (HEADS * NTOK * DH)

// ---------------- Kernel 1: proj = x @ W^T -> q (AoS, scaled), k (SoA) -----
// 512 blocks x 256 threads, 8 rows per block (2 blocks/CU for latency overlap)
__global__ __launch_bounds__(256) void k1_proj(const float* __restrict__ x,
                                               const float* __restrict__ W,
                                               float* __restrict__ qk) {
    __shared__ float xs[8 * 1028];         // pad 1024->1028 breaks bank aliasing
    const int t = threadIdx.x;
    const int row0 = blockIdx.x * 8;

    const float4* x4 = (const float4*)(x + (size_t)row0 * DIMC);
    #pragma unroll
    for (int i = 0; i < 8; ++i) {
        int f = t + i * 256;
        int r = f >> 8;
        int c4 = f & 255;
        float4 v = x4[f];
        *(float4*)(&xs[r * 1028 + c4 * 4]) = v;
    }
    __syncthreads();

    const int g  = t >> 2;                 // 0..63 -> owns o = 3g..3g+2
    const int rg = t & 3;                  // owns rows rg*2 .. rg*2+1

    float acc[2][3];
    #pragma unroll
    for (int a = 0; a < 2; ++a)
        #pragma unroll
        for (int m = 0; m < 3; ++m) acc[a][m] = 0.f;

    const float* w0 = W + (size_t)(3 * g) * DIMC;
    #pragma unroll 2
    for (int c = 0; c < DIMC; c += 4) {
        float4 w[3];
        #pragma unroll
        for (int m = 0; m < 3; ++m)
            w[m] = *(const float4*)(w0 + (size_t)m * DIMC + c);
        #pragma unroll
        for (int a = 0; a < 2; ++a) {
            float4 xv = *(const float4*)(&xs[(rg * 2 + a) * 1028 + c]);
            #pragma unroll
            for (int m = 0; m < 3; ++m) {
                acc[a][m] = fmaf(xv.x, w[m].x,
                            fmaf(xv.y, w[m].y,
                            fmaf(xv.z, w[m].z,
                            fmaf(xv.w, w[m].w, acc[a][m]))));
            }
        }
    }

    #pragma unroll
    for (int m = 0; m < 3; ++m) {
        int o   = 3 * g + m;
        int qkf = (o >= 96) ? 1 : 0;
        int oo  = o - 96 * qkf;
        int h   = oo >> 3;
        int d   = oo & 7;
        #pragma unroll
        for (int a = 0; a < 2; ++a) {
            int n = row0 + rg * 2 + a;
            float v = acc[a][m];
            if (!qkf) {
                qk[((size_t)h * NTOK + n) * DH + d] = v * QSCALE;      // Q AoS
            } else {
                qk[KOFF + ((size_t)h * DH + d) * NTOK + n] = v;        // K SoA
            }
        }
    }
}

// ---------------- Kernel 2: 8 rows per block, chunks descending ------------
__device__ __forceinline__ float log_sigmoid(float s) {
    float mn = fminf(s, 0.f);
    float z  = __builtin_amdgcn_exp2f(fabsf(s) * -LOG2E);   // = exp(-|s|)
    return mn - LN2 * __builtin_amdgcn_logf(1.f + z);       // log2 -> *ln2
}

__global__ __launch_bounds__(256) void k2_gates(const float* __restrict__ qk,
                                                float* __restrict__ out) {
    const int bid  = blockIdx.x;
    const int h    = bid >> 9;              // 512 blocks per head
    const int i0   = (bid & 511) << 3;      // 8 rows per block
    const int t    = threadIdx.x;
    const int lane = t & 63;
    const int wid  = t >> 6;

    __shared__ __align__(16) float qs[64];  // [r][d] for 8 rows
    __shared__ float wtot[2][4][8];         // [buf][wave][row]

    if (t < 64) {
        int r = t >> 3, d = t & 7;
        qs[t] = qk[((size_t)h * NTOK + i0 + r) * DH + d];
    }
    __syncthreads();

    const float* ks = qk + KOFF + (size_t)h * DH * NTOK;
    float* obase = out + ((size_t)h * NTOK + i0) * NTOK;

    float carry[8];
    #pragma unroll
    for (int r = 0; r < 8; ++r) carry[r] = 0.f;

    #pragma unroll
    for (int cc = 0; cc < 4; ++cc) {
        const int c  = 3 - cc;              // descending j chunks
        const int j0 = c * 1024 + 4 * t;
        float* op = obase + j0;

        if (1024 * c >= i0 + 7) {
            // chunk entirely >= all row indices: outputs are exactly 0
            float4 z; z.x = 0.f; z.y = 0.f; z.z = 0.f; z.w = 0.f;
            #pragma unroll
            for (int r = 0; r < 8; ++r)
                *(float4*)(op + (size_t)r * NTOK) = z;
        } else {
            // load k slice once, reuse for all 8 rows
            float4 kv[8];
            #pragma unroll
            for (int d = 0; d < 8; ++d)
                kv[d] = *(const float4*)(ks + (size_t)d * NTOK + j0);

            float ov[8][4], tot[8], tsave[8];
            #pragma unroll
            for (int r = 0; r < 8; ++r) {
                const int ir = i0 + r;
                float4 qa = *(const float4*)(&qs[r * 8]);       // broadcast
                float4 qb = *(const float4*)(&qs[r * 8 + 4]);
                float s0 = 0.f, s1 = 0.f, s2 = 0.f, s3 = 0.f;
                #pragma unroll
                for (int d = 0; d < 8; ++d) {
                    float qd = (d == 0) ? qa.x : (d == 1) ? qa.y : (d == 2) ? qa.z : (d == 3) ? qa.w
                             : (d == 4) ? qb.x : (d == 5) ? qb.y : (d == 6) ? qb.z : qb.w;
                    s0 = fmaf(qd, kv[d].x, s0);
                    s1 = fmaf(qd, kv[d].y, s1);
                    s2 = fmaf(qd, kv[d].z, s2);
                    s3 = fmaf(qd, kv[d].w, s3);
                }
                float g0 = (j0 + 0 < ir) ? log_sigmoid(s0) : 0.f;
                float g1 = (j0 + 1 < ir) ? log_sigmoid(s1) : 0.f;
                float g2 = (j0 + 2 < ir) ? log_sigmoid(s2) : 0.f;
                float g3 = (j0 + 3 < ir) ? log_sigmoid(s3) : 0.f;
                g2 += g3; g1 += g2; g0 += g1;          // reverse-inclusive suffix
                ov[r][0] = g0; ov[r][1] = g1; ov[r][2] = g2; ov[r][3] = g3;
                tot[r] = g0; tsave[r] = g0;
            }

            // wave-wide inclusive suffix scan, rounds outer / rows inner (8-way ILP)
            #pragma unroll
            for (int off = 1; off < 64; off <<= 1) {
                #pragma unroll
                for (int r = 0; r < 8; ++r) {
                    float v = __shfl_down(tot[r], off, 64);
                    if (lane + off < 64) tot[r] += v;
                }
            }

            if (lane == 0) {
                #pragma unroll
                for (int r = 0; r < 8; ++r) wtot[cc & 1][wid][r] = tot[r];
            }
            __syncthreads();

            #pragma unroll
            for (int r = 0; r < 8; ++r) {
                float w0 = wtot[cc & 1][0][r];
                float w1 = wtot[cc & 1][1][r];
                float w2 = wtot[cc & 1][2][r];
                float w3 = wtot[cc & 1][3][r];
                float later = (wid == 0) ? (w1 + w2 + w3)
                            : (wid == 1) ? (w2 + w3)
                            : (wid == 2) ? w3 : 0.f;
                float base = (tot[r] - tsave[r]) + later + carry[r];
                carry[r] += w0 + w1 + w2 + w3;
                float4 v;
                v.x = ov[r][0] + base;
                v.y = ov[r][1] + base;
                v.z = ov[r][2] + base;
                v.w = ov[r][3] + base;
                *(float4*)(op + (size_t)r * NTOK) = v;
            }
        }
    }
}

extern "C" void kernel_launch(void* const* d_in, const int* in_sizes, int n_in,
                              void* d_out, int out_size, void* d_ws, size_t ws_size,
                              hipStream_t stream) {
    const float* x = (const float*)d_in[0];
    const float* W = (const float*)d_in[1];
    float* out = (float*)d_out;
    float* qk  = (float*)d_ws;               // 3 MB scratch

    hipLaunchKernelGGL(k1_proj, dim3(NTOK / 8), dim3(256), 0, stream, x, W, qk);
    hipLaunchKernelGGL(k2_gates, dim3(HEADS * NTOK / 8), dim3(256), 0, stream, qk, out);
}

// Round 5
// 209.261 us; speedup vs baseline: 2.8018x; 1.0349x over previous
//
#include <hip/hip_runtime.h>

#define NTOK 4096
#define DIMC 1024
#define HEADS 12
#define DH 8
#define QSCALE 0.35355339059327373f   /* 8^-0.5 */
#define LOG2E  1.4426950408889634f
#define LN2    0.6931471805599453f

typedef float f4 __attribute__((ext_vector_type(4)));   // native vector for builtins

// ws layout (floats):
//   Q:  [h][n][8]   (pre-scaled by QSCALE), offset 0,      12*4096*8
//   K:  [h][d][n]   SoA,                    offset KOFF,   12*8*4096
#define KOFF (HEADS * NTOK * DH)

// ---------------- Kernel 1: proj = x @ W^T -> q (AoS, scaled), k (SoA) -----
__global__ __launch_bounds__(256) void k1_proj(const float* __restrict__ x,
                                               const float* __restrict__ W,
                                               float* __restrict__ qk) {
    __shared__ float xs[8 * 1028];         // pad 1024->1028 breaks bank aliasing
    const int t = threadIdx.x;
    const int row0 = blockIdx.x * 8;

    const f4* x4 = (const f4*)(x + (size_t)row0 * DIMC);
    #pragma unroll
    for (int i = 0; i < 8; ++i) {
        int f = t + i * 256;
        int r = f >> 8;
        int c4 = f & 255;
        f4 v = x4[f];
        *(f4*)(&xs[r * 1028 + c4 * 4]) = v;
    }
    __syncthreads();

    const int g  = t >> 2;                 // 0..63 -> owns o = 3g..3g+2
    const int rg = t & 3;                  // owns rows rg*2 .. rg*2+1

    float acc[2][3];
    #pragma unroll
    for (int a = 0; a < 2; ++a)
        #pragma unroll
        for (int m = 0; m < 3; ++m) acc[a][m] = 0.f;

    const float* w0 = W + (size_t)(3 * g) * DIMC;
    #pragma unroll 2
    for (int c = 0; c < DIMC; c += 4) {
        f4 w[3];
        #pragma unroll
        for (int m = 0; m < 3; ++m)
            w[m] = *(const f4*)(w0 + (size_t)m * DIMC + c);
        #pragma unroll
        for (int a = 0; a < 2; ++a) {
            f4 xv = *(const f4*)(&xs[(rg * 2 + a) * 1028 + c]);
            #pragma unroll
            for (int m = 0; m < 3; ++m) {
                acc[a][m] = fmaf(xv.x, w[m].x,
                            fmaf(xv.y, w[m].y,
                            fmaf(xv.z, w[m].z,
                            fmaf(xv.w, w[m].w, acc[a][m]))));
            }
        }
    }

    #pragma unroll
    for (int m = 0; m < 3; ++m) {
        int o   = 3 * g + m;
        int qkf = (o >= 96) ? 1 : 0;
        int oo  = o - 96 * qkf;
        int h   = oo >> 3;
        int d   = oo & 7;
        #pragma unroll
        for (int a = 0; a < 2; ++a) {
            int n = row0 + rg * 2 + a;
            float v = acc[a][m];
            if (!qkf) {
                qk[((size_t)h * NTOK + n) * DH + d] = v * QSCALE;      // Q AoS
            } else {
                qk[KOFF + ((size_t)h * DH + d) * NTOK + n] = v;        // K SoA
            }
        }
    }
}

// ---------------- Kernel 2: fully wave-independent, 2 rows per wave --------
__device__ __forceinline__ float log_sigmoid(float s) {
    float mn = fminf(s, 0.f);
    float z  = __builtin_amdgcn_exp2f(fabsf(s) * -LOG2E);   // = exp(-|s|)
    return mn - LN2 * __builtin_amdgcn_logf(1.f + z);       // log2 -> *ln2
}

__global__ __launch_bounds__(256) void k2_gates(const float* __restrict__ qk,
                                                float* __restrict__ out) {
    const int bid  = blockIdx.x;
    const int h    = bid >> 9;              // 512 blocks per head
    const int i0   = (bid & 511) << 3;      // 8 rows per block
    const int t    = threadIdx.x;
    const int lane = t & 63;
    const int wid  = t >> 6;
    const int r0   = i0 + 2 * wid;          // this wave owns rows r0, r0+1

    const float* qrow = qk + ((size_t)h * NTOK + r0) * DH;
    float qa[8], qb[8];
    #pragma unroll
    for (int d = 0; d < 8; ++d) { qa[d] = qrow[d]; qb[d] = qrow[DH + d]; }

    const float* ks = qk + KOFF + (size_t)h * DH * NTOK;
    float* o0 = out + ((size_t)h * NTOK + r0) * NTOK;
    float* o1 = o0 + NTOK;

    const int ccmax = r0 >> 8;              // last chunk with any j < r0+1

    // ---- upper-triangle chunks: pure zero stores (branch-free, no compute)
    f4 z = (f4)(0.f);
    for (int cc = 15; cc > ccmax; --cc) {
        const int j0 = cc * 256 + 4 * lane;
        __builtin_nontemporal_store(z, (f4*)(o0 + j0));
        __builtin_nontemporal_store(z, (f4*)(o1 + j0));
    }

    // ---- computed chunks, descending, carry per row; all intra-wave -------
    float carry0 = 0.f, carry1 = 0.f;
    for (int cc = ccmax; cc >= 0; --cc) {
        const int j0 = cc * 256 + 4 * lane;

        f4 kv[8];
        #pragma unroll
        for (int d = 0; d < 8; ++d)
            kv[d] = *(const f4*)(ks + (size_t)d * NTOK + j0);

        float a0 = 0.f, a1 = 0.f, a2 = 0.f, a3 = 0.f;
        float b0 = 0.f, b1 = 0.f, b2 = 0.f, b3 = 0.f;
        #pragma unroll
        for (int d = 0; d < 8; ++d) {
            a0 = fmaf(qa[d], kv[d].x, a0);
            a1 = fmaf(qa[d], kv[d].y, a1);
            a2 = fmaf(qa[d], kv[d].z, a2);
            a3 = fmaf(qa[d], kv[d].w, a3);
            b0 = fmaf(qb[d], kv[d].x, b0);
            b1 = fmaf(qb[d], kv[d].y, b1);
            b2 = fmaf(qb[d], kv[d].z, b2);
            b3 = fmaf(qb[d], kv[d].w, b3);
        }

        float g0[4], g1[4];
        g0[0] = (j0 + 0 < r0) ? log_sigmoid(a0) : 0.f;
        g0[1] = (j0 + 1 < r0) ? log_sigmoid(a1) : 0.f;
        g0[2] = (j0 + 2 < r0) ? log_sigmoid(a2) : 0.f;
        g0[3] = (j0 + 3 < r0) ? log_sigmoid(a3) : 0.f;
        const int r1 = r0 + 1;
        g1[0] = (j0 + 0 < r1) ? log_sigmoid(b0) : 0.f;
        g1[1] = (j0 + 1 < r1) ? log_sigmoid(b1) : 0.f;
        g1[2] = (j0 + 2 < r1) ? log_sigmoid(b2) : 0.f;
        g1[3] = (j0 + 3 < r1) ? log_sigmoid(b3) : 0.f;

        // local reverse-inclusive suffix within the 4-elem group
        g0[2] += g0[3]; g0[1] += g0[2]; g0[0] += g0[1];
        g1[2] += g1[3]; g1[1] += g1[2]; g1[0] += g1[1];
        const float t0 = g0[0], t1 = g1[0];

        // intra-wave inclusive suffix scan of per-lane totals (2 rows, ILP)
        float s0 = t0, s1 = t1;
        #pragma unroll
        for (int off = 1; off < 64; off <<= 1) {
            float v0 = __shfl_down(s0, off, 64);
            float v1 = __shfl_down(s1, off, 64);
            if (lane + off < 64) { s0 += v0; s1 += v1; }
        }
        const float base0 = (s0 - t0) + carry0;   // strictly-later lanes + later chunks
        const float base1 = (s1 - t1) + carry1;
        carry0 += __shfl(s0, 0, 64);              // chunk total
        carry1 += __shfl(s1, 0, 64);

        f4 v0, v1;
        v0.x = g0[0] + base0; v0.y = g0[1] + base0;
        v0.z = g0[2] + base0; v0.w = g0[3] + base0;
        v1.x = g1[0] + base1; v1.y = g1[1] + base1;
        v1.z = g1[2] + base1; v1.w = g1[3] + base1;
        __builtin_nontemporal_store(v0, (f4*)(o0 + j0));
        __builtin_nontemporal_store(v1, (f4*)(o1 + j0));
    }
}

extern "C" void kernel_launch(void* const* d_in, const int* in_sizes, int n_in,
                              void* d_out, int out_size, void* d_ws, size_t ws_size,
                              hipStream_t stream) {
    const float* x = (const float*)d_in[0];
    const float* W = (const float*)d_in[1];
    float* out = (float*)d_out;
    float* qk  = (float*)d_ws;               // 3 MB scratch

    hipLaunchKernelGGL(k1_proj, dim3(NTOK / 8), dim3(256), 0, stream, x, W, qk);
    hipLaunchKernelGGL(k2_gates, dim3(HEADS * NTOK / 8), dim3(256), 0, stream, qk, out);
}